// Round 3
// baseline (471.263 us; speedup 1.0000x reference)
//
#include <hip/hip_runtime.h>
#include <stdint.h>

#define B_ 4
#define N_ 1024
#define C_ 768
#define H_ 12
#define D_ 64
#define MT 4096   // B_*N_ tokens

typedef short bf16x8 __attribute__((ext_vector_type(8)));
typedef float f32x4  __attribute__((ext_vector_type(4)));
typedef unsigned short u16;

__device__ __forceinline__ u16 f2bf(float f) {
  union { float f; uint32_t u; } v; v.f = f;
  uint32_t u = v.u + 0x7FFFu + ((v.u >> 16) & 1u);   // RNE
  return (u16)(u >> 16);
}

__device__ __forceinline__ void gload16(const void* g, void* l) {
  __builtin_amdgcn_global_load_lds(
      (const __attribute__((address_space(1))) void*)g,
      (__attribute__((address_space(3))) void*)l, 16, 0, 0);
}

// stage ROWS x 64 bf16 tile (row-major, row stride ld elems) into LDS via global_load_lds.
template<int ROWS, int NW>
__device__ __forceinline__ void stage_bt(const u16* g, int ld, u16 (*lds)[64]) {
  const int lane = threadIdx.x & 63, wv = threadIdx.x >> 6;
  const int r8 = lane >> 3;          // 0..7 row within 8-row chunk
  const int c8 = (lane & 7) * 8;     // 16B per lane
  for (int i = wv; i < ROWS / 8; i += NW)
    gload16(g + (size_t)(i * 8 + r8) * ld + c8, &lds[i * 8][0]);
}

// one K=64 MFMA step: each wave computes a 64x64 sub-tile (4x4 frags of 16x16x32).
template<int WM, int WN>
__device__ __forceinline__ void mma_step(const u16 (*As)[64], const u16 (*Bs)[64],
                                         f32x4 acc[4][4]) {
  const int lane = threadIdx.x & 63, wv = threadIdx.x >> 6;
  const int wr = wv / WN, wc = wv % WN;
  const int g4 = lane >> 4, r16 = lane & 15;
  #pragma unroll
  for (int ks = 0; ks < 2; ++ks) {
    bf16x8 a[4], b[4];
    #pragma unroll
    for (int mi = 0; mi < 4; ++mi)
      a[mi] = *(const bf16x8*)&As[wr * 64 + mi * 16 + r16][ks * 32 + g4 * 8];
    #pragma unroll
    for (int ni = 0; ni < 4; ++ni)
      b[ni] = *(const bf16x8*)&Bs[wc * 64 + ni * 16 + r16][ks * 32 + g4 * 8];
    #pragma unroll
    for (int mi = 0; mi < 4; ++mi)
      #pragma unroll
      for (int ni = 0; ni < 4; ++ni)
        acc[mi][ni] = __builtin_amdgcn_mfma_f32_16x16x32_bf16(a[mi], b[ni], acc[mi][ni], 0, 0, 0);
  }
}

// ---------------- prep kernels ----------------
__global__ __launch_bounds__(256) void cvt_bf16(const float* __restrict__ in,
                                                u16* __restrict__ out, int n4) {
  int i = blockIdx.x * 256 + threadIdx.x;
  if (i < n4) {
    float4 v = *(const float4*)&in[(size_t)i * 4];
    *(ushort4*)&out[(size_t)i * 4] = make_ushort4(f2bf(v.x), f2bf(v.y), f2bf(v.z), f2bf(v.w));
  }
}

__global__ __launch_bounds__(256) void transpose_bf16(const float* __restrict__ in,
                                                      u16* __restrict__ out, int R, int Cc) {
  __shared__ float tile[32][33];
  const int bx = blockIdx.x * 32, by = blockIdx.y * 32;
  const int tx = threadIdx.x, ty = threadIdx.y;
  #pragma unroll
  for (int i = 0; i < 32; i += 8)
    tile[ty + i][tx] = in[(size_t)(by + ty + i) * Cc + bx + tx];
  __syncthreads();
  #pragma unroll
  for (int i = 0; i < 32; i += 8)
    out[(size_t)(bx + ty + i) * R + by + tx] = f2bf(tile[tx][ty + i]);
}

// bf16 [b][n][c] -> [b][c][n]  (c = h*64+d), 32x32 tiles
__global__ __launch_bounds__(256) void transpose_v(const u16* __restrict__ Vb,
                                                   u16* __restrict__ Vt) {
  __shared__ u16 tile[32][33];
  const int b = blockIdx.z;
  const int cx = blockIdx.x * 32, ny = blockIdx.y * 32;
  const int tx = threadIdx.x, ty = threadIdx.y;
  #pragma unroll
  for (int i = 0; i < 32; i += 8)
    tile[ty + i][tx] = Vb[((size_t)b * N_ + ny + ty + i) * C_ + cx + tx];
  __syncthreads();
  #pragma unroll
  for (int i = 0; i < 32; i += 8)
    Vt[((size_t)b * C_ + cx + ty + i) * N_ + ny + tx] = tile[tx][ty + i];
}

// ---------------- qkv GEMM: [4096,768] x [768,2304] + bias ----------------
__global__ __launch_bounds__(256) void qkv_gemm(const u16* __restrict__ xbf,
    const u16* __restrict__ Wt, const float* __restrict__ bias,
    u16* __restrict__ Qb, u16* __restrict__ Kb, u16* __restrict__ Vb) {
  __shared__ u16 As[128][64], Bs[128][64];
  f32x4 acc[4][4] = {};
  const int row0 = blockIdx.y * 128, col0 = blockIdx.x * 128;
  const u16* Ab = xbf + (size_t)row0 * C_;
  const u16* Bb = Wt + (size_t)col0 * C_;
  for (int k0 = 0; k0 < C_; k0 += 64) {
    stage_bt<128, 4>(Ab + k0, C_, As);
    stage_bt<128, 4>(Bb + k0, C_, Bs);
    __syncthreads();
    mma_step<2, 2>(As, Bs, acc);
    __syncthreads();
  }
  const int lane = threadIdx.x & 63, wv = threadIdx.x >> 6;
  const int wr = wv >> 1, wc = wv & 1;
  const int part = col0 / C_;    // block fully inside one of q/k/v
  #pragma unroll
  for (int mi = 0; mi < 4; ++mi)
  #pragma unroll
  for (int ni = 0; ni < 4; ++ni) {
    const int c = col0 + wc * 64 + ni * 16 + (lane & 15);
    const int rb = row0 + wr * 64 + mi * 16 + (lane >> 4) * 4;
    const float bv = bias[c];
    #pragma unroll
    for (int rr = 0; rr < 4; ++rr) {
      const int row = rb + rr;
      const float v = acc[mi][ni][rr] + bv;
      if (part == 0) {
        Qb[(size_t)row * C_ + c] = f2bf(v * 0.125f);
      } else if (part == 1) {
        Kb[(size_t)row * C_ + (c - C_)] = f2bf(v);
      } else {
        Vb[(size_t)row * C_ + (c - 2 * C_)] = f2bf(v);
      }
    }
  }
}

// ---------------- QK^T (batched over b,h): logits fp32 into d_out attn region ----------------
__global__ __launch_bounds__(256) void qk_gemm(const u16* __restrict__ Qb,
    const u16* __restrict__ Kb, float* __restrict__ Sf) {
  __shared__ u16 As[128][64], Bs[128][64];
  f32x4 acc[4][4] = {};
  const int z = blockIdx.z, b = z / H_, h = z % H_;
  const int row0 = blockIdx.y * 128, col0 = blockIdx.x * 128;
  const u16* Ab = Qb + (size_t)(b * N_ + row0) * C_ + h * D_;
  const u16* Bb = Kb + (size_t)(b * N_ + col0) * C_ + h * D_;
  stage_bt<128, 4>(Ab, C_, As);
  stage_bt<128, 4>(Bb, C_, Bs);
  __syncthreads();
  mma_step<2, 2>(As, Bs, acc);
  float* Sp = Sf + (size_t)z * N_ * N_;
  const int lane = threadIdx.x & 63, wv = threadIdx.x >> 6;
  const int wr = wv >> 1, wc = wv & 1;
  #pragma unroll
  for (int mi = 0; mi < 4; ++mi)
  #pragma unroll
  for (int ni = 0; ni < 4; ++ni) {
    const int c = col0 + wc * 64 + ni * 16 + (lane & 15);
    const int rb = row0 + wr * 64 + mi * 16 + (lane >> 4) * 4;
    #pragma unroll
    for (int rr = 0; rr < 4; ++rr)
      Sp[(size_t)(rb + rr) * N_ + c] = acc[mi][ni][rr];
  }
}

// ------- fused talking-heads: mix1 -> softmax -> mix2, fp32 in place, no LDS staging -------
__global__ __launch_bounds__(256, 4) void talking_softmax(float* __restrict__ attnP,
        const float* __restrict__ Wl, const float* __restrict__ bl,
        const float* __restrict__ Ww, const float* __restrict__ bw) {
    __shared__ float Wl_s[H_ * H_], Ww_s[H_ * H_];
    __shared__ float bl_s[H_], bw_s[H_];
    __shared__ float redA[H_][4], redB[H_][4];
    const int tid = threadIdx.x;
    const int r = blockIdx.x;
    const int b = r >> 10, n = r & 1023;
    if (tid < H_ * H_) { Wl_s[tid] = Wl[tid]; Ww_s[tid] = Ww[tid]; }
    if (tid < H_)      { bl_s[tid] = bl[tid]; bw_s[tid] = bw[tid]; }
    __syncthreads();
    const size_t rowbase = ((size_t)(b * H_) * N_ + n) * N_;

    // mix1 directly from global (coalesced float4 per plane)
    float T[48];
    #pragma unroll
    for (int k = 0; k < H_; ++k) {
        float bk = bl_s[k];
        T[k*4+0] = bk; T[k*4+1] = bk; T[k*4+2] = bk; T[k*4+3] = bk;
    }
    #pragma unroll
    for (int h = 0; h < H_; ++h) {
        float4 sv = *(const float4*)&attnP[rowbase + (size_t)h * N_ * N_ + tid * 4];
        #pragma unroll
        for (int k = 0; k < H_; ++k) {
            float w = Wl_s[h * H_ + k];
            T[k*4+0] += sv.x * w; T[k*4+1] += sv.y * w;
            T[k*4+2] += sv.z * w; T[k*4+3] += sv.w * w;
        }
    }

    const int lane = tid & 63, wv = tid >> 6;
    #pragma unroll
    for (int k = 0; k < H_; ++k) {
        float m = fmaxf(fmaxf(T[k*4+0], T[k*4+1]), fmaxf(T[k*4+2], T[k*4+3]));
        #pragma unroll
        for (int off = 32; off > 0; off >>= 1) m = fmaxf(m, __shfl_xor(m, off));
        if (lane == 0) redA[k][wv] = m;
    }
    __syncthreads();
    float pmax[12];
    #pragma unroll
    for (int k = 0; k < H_; ++k)
        pmax[k] = fmaxf(fmaxf(redA[k][0], redA[k][1]), fmaxf(redA[k][2], redA[k][3]));
    #pragma unroll
    for (int k = 0; k < H_; ++k) {
        T[k*4+0] = __expf(T[k*4+0] - pmax[k]);
        T[k*4+1] = __expf(T[k*4+1] - pmax[k]);
        T[k*4+2] = __expf(T[k*4+2] - pmax[k]);
        T[k*4+3] = __expf(T[k*4+3] - pmax[k]);
        float s = (T[k*4+0] + T[k*4+1]) + (T[k*4+2] + T[k*4+3]);
        #pragma unroll
        for (int off = 32; off > 0; off >>= 1) s += __shfl_xor(s, off);
        if (lane == 0) redB[k][wv] = s;
    }
    __syncthreads();
    #pragma unroll
    for (int k = 0; k < H_; ++k) {
        float inv = 1.0f / ((redB[k][0] + redB[k][1]) + (redB[k][2] + redB[k][3]));
        T[k*4+0] *= inv; T[k*4+1] *= inv; T[k*4+2] *= inv; T[k*4+3] *= inv;
    }
    #pragma unroll
    for (int jj = 0; jj < H_; ++jj) {
        float u0 = bw_s[jj], u1 = u0, u2 = u0, u3 = u0;
        #pragma unroll
        for (int k = 0; k < H_; ++k) {
            float w = Ww_s[k * H_ + jj];
            u0 += T[k*4+0] * w; u1 += T[k*4+1] * w;
            u2 += T[k*4+2] * w; u3 += T[k*4+3] * w;
        }
        *(float4*)&attnP[rowbase + (size_t)jj * N_ * N_ + tid * 4] =
            make_float4(u0, u1, u2, u3);
    }
}

// ---------------- PV (batched): A = fp32 attn (converted on the fly), B = Vt bf16 ----------------
__global__ __launch_bounds__(128) void pv_gemm(const float* __restrict__ Pf,
    const u16* __restrict__ Vt, u16* __restrict__ Oh) {
  __shared__ u16 As[128][64], Bs[64][64];
  f32x4 acc[4][4] = {};
  const int z = blockIdx.y, b = z / H_, h = z % H_;
  const int row0 = blockIdx.x * 128;
  const float* Ap = Pf + (size_t)z * N_ * N_ + (size_t)row0 * N_;
  const u16* Bb = Vt + (size_t)z * D_ * N_;
  const int tid = threadIdx.x;
  for (int k0 = 0; k0 < N_; k0 += 64) {
    #pragma unroll
    for (int i = 0; i < 16; ++i) {
      const int row = i * 8 + (tid >> 4);
      const int c4 = (tid & 15) * 4;
      float4 v = *(const float4*)&Ap[(size_t)row * N_ + k0 + c4];
      *(ushort4*)&As[row][c4] = make_ushort4(f2bf(v.x), f2bf(v.y), f2bf(v.z), f2bf(v.w));
    }
    stage_bt<64, 2>(Bb + k0, N_, Bs);
    __syncthreads();
    mma_step<2, 1>(As, Bs, acc);
    __syncthreads();
  }
  const int lane = tid & 63, wv = tid >> 6;
  #pragma unroll
  for (int mi = 0; mi < 4; ++mi)
  #pragma unroll
  for (int ni = 0; ni < 4; ++ni) {
    const int c = ni * 16 + (lane & 15);
    const int rb = row0 + wv * 64 + mi * 16 + (lane >> 4) * 4;
    #pragma unroll
    for (int rr = 0; rr < 4; ++rr)
      Oh[(size_t)(b * N_ + rb + rr) * C_ + h * D_ + c] = f2bf(acc[mi][ni][rr]);
  }
}

// ---------------- proj GEMM: [4096,768] x [768,768] + bias -> fp32 out ----------------
__global__ __launch_bounds__(128) void proj_gemm(const u16* __restrict__ Oh,
    const u16* __restrict__ Wt, const float* __restrict__ bias, float* __restrict__ out) {
  __shared__ u16 As[64][64], Bs[128][64];
  f32x4 acc[4][4] = {};
  const int row0 = blockIdx.y * 64, col0 = blockIdx.x * 128;
  const u16* Ab = Oh + (size_t)row0 * C_;
  const u16* Bb = Wt + (size_t)col0 * C_;
  for (int k0 = 0; k0 < C_; k0 += 64) {
    stage_bt<64, 2>(Ab + k0, C_, As);
    stage_bt<128, 2>(Bb + k0, C_, Bs);
    __syncthreads();
    mma_step<1, 2>(As, Bs, acc);
    __syncthreads();
  }
  const int lane = threadIdx.x & 63, wv = threadIdx.x >> 6;
  const int wc = wv & 1;
  #pragma unroll
  for (int mi = 0; mi < 4; ++mi)
  #pragma unroll
  for (int ni = 0; ni < 4; ++ni) {
    const int c = col0 + wc * 64 + ni * 16 + (lane & 15);
    const int rb = row0 + mi * 16 + (lane >> 4) * 4;
    const float bv = bias[c];
    #pragma unroll
    for (int rr = 0; rr < 4; ++rr)
      out[(size_t)(rb + rr) * C_ + c] = acc[mi][ni][rr] + bv;
  }
}

extern "C" void kernel_launch(void* const* d_in, const int* in_sizes, int n_in,
                              void* d_out, int out_size, void* d_ws, size_t ws_size,
                              hipStream_t stream) {
  const float* x     = (const float*)d_in[0];
  const float* Wqkv  = (const float*)d_in[1];
  const float* bqkv  = (const float*)d_in[2];
  const float* Wl    = (const float*)d_in[3];
  const float* bl    = (const float*)d_in[4];
  const float* Ww    = (const float*)d_in[5];
  const float* bw    = (const float*)d_in[6];
  const float* Wproj = (const float*)d_in[7];
  const float* bproj = (const float*)d_in[8];

  float* out   = (float*)d_out;
  float* attnP = out + (size_t)MT * C_;            // logits scratch == final attn output

  u16* xbf = (u16*)d_ws;                           // [4096][768]
  u16* Wqt = xbf + (size_t)MT * C_;                // [2304][768] = W_qkv^T
  u16* Wpt = Wqt + (size_t)3 * C_ * C_;            // [768][768]  = W_proj^T
  u16* Qb  = Wpt + (size_t)C_ * C_;                // [4096][768] (scaled)
  u16* Kb  = Qb + (size_t)MT * C_;                 // [4096][768]
  u16* Vb  = Kb + (size_t)MT * C_;                 // [4096][768] row-major
  u16* Vtb = Vb + (size_t)MT * C_;                 // [b][h][d][n]
  u16* Oh  = Vtb + (size_t)MT * C_;                // [4096][768]
  // total ws use: ~42.5 MB

  cvt_bf16<<<(MT * C_ / 4 + 255) / 256, 256, 0, stream>>>(x, xbf, MT * C_ / 4);
  transpose_bf16<<<dim3(3 * C_ / 32, C_ / 32), dim3(32, 8), 0, stream>>>(Wqkv, Wqt, C_, 3 * C_);
  transpose_bf16<<<dim3(C_ / 32, C_ / 32), dim3(32, 8), 0, stream>>>(Wproj, Wpt, C_, C_);

  qkv_gemm<<<dim3(3 * C_ / 128, MT / 128), 256, 0, stream>>>(xbf, Wqt, bqkv, Qb, Kb, Vb);
  transpose_v<<<dim3(C_ / 32, N_ / 32, B_), dim3(32, 8), 0, stream>>>(Vb, Vtb);
  qk_gemm<<<dim3(N_ / 128, N_ / 128, B_ * H_), 256, 0, stream>>>(Qb, Kb, attnP);
  talking_softmax<<<MT, 256, 0, stream>>>(attnP, Wl, bl, Ww, bw);
  pv_gemm<<<dim3(N_ / 128, B_ * H_), 128, 0, stream>>>(attnP, Vtb, Oh);
  proj_gemm<<<dim3(C_ / 128, MT / 64), 128, 0, stream>>>(Oh, Wpt, bproj, out);
}

// Round 4
// 257.360 us; speedup vs baseline: 1.8311x; 1.8311x over previous
//
#include <hip/hip_runtime.h>
#include <stdint.h>

#define B_ 4
#define N_ 1024
#define C_ 768
#define H_ 12
#define D_ 64
#define MT 4096   // B_*N_ tokens

typedef short bf16x8 __attribute__((ext_vector_type(8)));
typedef float f32x4  __attribute__((ext_vector_type(4)));
typedef unsigned short u16;

__device__ __forceinline__ u16 f2bf(float f) {
  union { float f; uint32_t u; } v; v.f = f;
  uint32_t u = v.u + 0x7FFFu + ((v.u >> 16) & 1u);   // RNE
  return (u16)(u >> 16);
}

__device__ __forceinline__ void gload16(const void* g, void* l) {
  __builtin_amdgcn_global_load_lds(
      (const __attribute__((address_space(1))) void*)g,
      (__attribute__((address_space(3))) void*)l, 16, 0, 0);
}

// stage ROWS x 64 bf16 tile (row-major, row stride ld elems) into LDS via global_load_lds.
template<int ROWS, int NW>
__device__ __forceinline__ void stage_bt(const u16* g, int ld, u16 (*lds)[64]) {
  const int lane = threadIdx.x & 63, wv = threadIdx.x >> 6;
  const int r8 = lane >> 3;          // 0..7 row within 8-row chunk
  const int c8 = (lane & 7) * 8;     // 16B per lane
  for (int i = wv; i < ROWS / 8; i += NW)
    gload16(g + (size_t)(i * 8 + r8) * ld + c8, &lds[i * 8][0]);
}

// one K=64 MFMA step: each wave computes a 64x64 sub-tile (4x4 frags of 16x16x32).
template<int WM, int WN>
__device__ __forceinline__ void mma_step(const u16 (*As)[64], const u16 (*Bs)[64],
                                         f32x4 acc[4][4]) {
  const int lane = threadIdx.x & 63, wv = threadIdx.x >> 6;
  const int wr = wv / WN, wc = wv % WN;
  const int g4 = lane >> 4, r16 = lane & 15;
  #pragma unroll
  for (int ks = 0; ks < 2; ++ks) {
    bf16x8 a[4], b[4];
    #pragma unroll
    for (int mi = 0; mi < 4; ++mi)
      a[mi] = *(const bf16x8*)&As[wr * 64 + mi * 16 + r16][ks * 32 + g4 * 8];
    #pragma unroll
    for (int ni = 0; ni < 4; ++ni)
      b[ni] = *(const bf16x8*)&Bs[wc * 64 + ni * 16 + r16][ks * 32 + g4 * 8];
    #pragma unroll
    for (int mi = 0; mi < 4; ++mi)
      #pragma unroll
      for (int ni = 0; ni < 4; ++ni)
        acc[mi][ni] = __builtin_amdgcn_mfma_f32_16x16x32_bf16(a[mi], b[ni], acc[mi][ni], 0, 0, 0);
  }
}

// ---------------- prep kernels ----------------
__global__ __launch_bounds__(256) void cvt_bf16(const float* __restrict__ in,
                                                u16* __restrict__ out, int n4) {
  int i = blockIdx.x * 256 + threadIdx.x;
  if (i < n4) {
    float4 v = *(const float4*)&in[(size_t)i * 4];
    *(ushort4*)&out[(size_t)i * 4] = make_ushort4(f2bf(v.x), f2bf(v.y), f2bf(v.z), f2bf(v.w));
  }
}

__global__ __launch_bounds__(256) void transpose_bf16(const float* __restrict__ in,
                                                      u16* __restrict__ out, int R, int Cc) {
  __shared__ float tile[32][33];
  const int bx = blockIdx.x * 32, by = blockIdx.y * 32;
  const int tx = threadIdx.x, ty = threadIdx.y;
  #pragma unroll
  for (int i = 0; i < 32; i += 8)
    tile[ty + i][tx] = in[(size_t)(by + ty + i) * Cc + bx + tx];
  __syncthreads();
  #pragma unroll
  for (int i = 0; i < 32; i += 8)
    out[(size_t)(bx + ty + i) * R + by + tx] = f2bf(tile[tx][ty + i]);
}

// bf16 [b][n][c] -> [b][c][n]  (c = h*64+d), 32x32 tiles
__global__ __launch_bounds__(256) void transpose_v(const u16* __restrict__ Vb,
                                                   u16* __restrict__ Vt) {
  __shared__ u16 tile[32][33];
  const int b = blockIdx.z;
  const int cx = blockIdx.x * 32, ny = blockIdx.y * 32;
  const int tx = threadIdx.x, ty = threadIdx.y;
  #pragma unroll
  for (int i = 0; i < 32; i += 8)
    tile[ty + i][tx] = Vb[((size_t)b * N_ + ny + ty + i) * C_ + cx + tx];
  __syncthreads();
  #pragma unroll
  for (int i = 0; i < 32; i += 8)
    Vt[((size_t)b * C_ + cx + ty + i) * N_ + ny + tx] = tile[tx][ty + i];
}

// ---------------- qkv GEMM: [4096,768] x [768,2304] + bias ----------------
__global__ __launch_bounds__(256) void qkv_gemm(const u16* __restrict__ xbf,
    const u16* __restrict__ Wt, const float* __restrict__ bias,
    u16* __restrict__ Qb, u16* __restrict__ Kb, u16* __restrict__ Vb) {
  __shared__ u16 As[128][64], Bs[128][64];
  f32x4 acc[4][4] = {};
  const int row0 = blockIdx.y * 128, col0 = blockIdx.x * 128;
  const u16* Ab = xbf + (size_t)row0 * C_;
  const u16* Bb = Wt + (size_t)col0 * C_;
  for (int k0 = 0; k0 < C_; k0 += 64) {
    stage_bt<128, 4>(Ab + k0, C_, As);
    stage_bt<128, 4>(Bb + k0, C_, Bs);
    __syncthreads();
    mma_step<2, 2>(As, Bs, acc);
    __syncthreads();
  }
  const int lane = threadIdx.x & 63, wv = threadIdx.x >> 6;
  const int wr = wv >> 1, wc = wv & 1;
  const int part = col0 / C_;    // block fully inside one of q/k/v
  #pragma unroll
  for (int mi = 0; mi < 4; ++mi)
  #pragma unroll
  for (int ni = 0; ni < 4; ++ni) {
    const int c = col0 + wc * 64 + ni * 16 + (lane & 15);
    const int rb = row0 + wr * 64 + mi * 16 + (lane >> 4) * 4;
    const float bv = bias[c];
    #pragma unroll
    for (int rr = 0; rr < 4; ++rr) {
      const int row = rb + rr;
      const float v = acc[mi][ni][rr] + bv;
      if (part == 0) {
        Qb[(size_t)row * C_ + c] = f2bf(v * 0.125f);
      } else if (part == 1) {
        Kb[(size_t)row * C_ + (c - C_)] = f2bf(v);
      } else {
        Vb[(size_t)row * C_ + (c - 2 * C_)] = f2bf(v);
      }
    }
  }
}

// ---------------- QK^T (batched over b,h): logits fp32 into d_out attn region ----------------
__global__ __launch_bounds__(256) void qk_gemm(const u16* __restrict__ Qb,
    const u16* __restrict__ Kb, float* __restrict__ Sf) {
  __shared__ u16 As[128][64], Bs[128][64];
  f32x4 acc[4][4] = {};
  const int z = blockIdx.z, b = z / H_, h = z % H_;
  const int row0 = blockIdx.y * 128, col0 = blockIdx.x * 128;
  const u16* Ab = Qb + (size_t)(b * N_ + row0) * C_ + h * D_;
  const u16* Bb = Kb + (size_t)(b * N_ + col0) * C_ + h * D_;
  stage_bt<128, 4>(Ab, C_, As);
  stage_bt<128, 4>(Bb, C_, Bs);
  __syncthreads();
  mma_step<2, 2>(As, Bs, acc);
  float* Sp = Sf + (size_t)z * N_ * N_;
  const int lane = threadIdx.x & 63, wv = threadIdx.x >> 6;
  const int wr = wv >> 1, wc = wv & 1;
  #pragma unroll
  for (int mi = 0; mi < 4; ++mi)
  #pragma unroll
  for (int ni = 0; ni < 4; ++ni) {
    const int c = col0 + wc * 64 + ni * 16 + (lane & 15);
    const int rb = row0 + wr * 64 + mi * 16 + (lane >> 4) * 4;
    #pragma unroll
    for (int rr = 0; rr < 4; ++rr)
      Sp[(size_t)(rb + rr) * N_ + c] = acc[mi][ni][rr];
  }
}

// ------- fused talking-heads: mix1 -> softmax -> mix2, fp32 in place, registers only -------
// __launch_bounds__(256,2): <=256 VGPR cap — MUST NOT spill T[48] (r3 lesson: (256,4)
// forced 64 VGPRs -> ~20 regs spilled to scratch -> 3x HBM traffic, 2.4x slower).
__global__ __launch_bounds__(256, 2) void talking_softmax(float* __restrict__ attnP,
        const float* __restrict__ Wl, const float* __restrict__ bl,
        const float* __restrict__ Ww, const float* __restrict__ bw) {
    __shared__ float Wl_s[H_ * H_], Ww_s[H_ * H_];
    __shared__ float bl_s[H_], bw_s[H_];
    __shared__ float redA[H_][4], redB[H_][4];
    const int tid = threadIdx.x;
    const int r = blockIdx.x;
    const int b = r >> 10, n = r & 1023;
    if (tid < H_ * H_) { Wl_s[tid] = Wl[tid]; Ww_s[tid] = Ww[tid]; }
    if (tid < H_)      { bl_s[tid] = bl[tid]; bw_s[tid] = bw[tid]; }
    __syncthreads();
    const size_t rowbase = ((size_t)(b * H_) * N_ + n) * N_;

    // mix1 directly from global (coalesced float4 per plane)
    float T[48];
    #pragma unroll
    for (int k = 0; k < H_; ++k) {
        float bk = bl_s[k];
        T[k*4+0] = bk; T[k*4+1] = bk; T[k*4+2] = bk; T[k*4+3] = bk;
    }
    #pragma unroll
    for (int h = 0; h < H_; ++h) {
        float4 sv = *(const float4*)&attnP[rowbase + (size_t)h * N_ * N_ + tid * 4];
        #pragma unroll
        for (int k = 0; k < H_; ++k) {
            float w = Wl_s[h * H_ + k];
            T[k*4+0] += sv.x * w; T[k*4+1] += sv.y * w;
            T[k*4+2] += sv.z * w; T[k*4+3] += sv.w * w;
        }
    }

    const int lane = tid & 63, wv = tid >> 6;
    #pragma unroll
    for (int k = 0; k < H_; ++k) {
        float m = fmaxf(fmaxf(T[k*4+0], T[k*4+1]), fmaxf(T[k*4+2], T[k*4+3]));
        #pragma unroll
        for (int off = 32; off > 0; off >>= 1) m = fmaxf(m, __shfl_xor(m, off));
        if (lane == 0) redA[k][wv] = m;
    }
    __syncthreads();
    float pmax[12];
    #pragma unroll
    for (int k = 0; k < H_; ++k)
        pmax[k] = fmaxf(fmaxf(redA[k][0], redA[k][1]), fmaxf(redA[k][2], redA[k][3]));
    #pragma unroll
    for (int k = 0; k < H_; ++k) {
        T[k*4+0] = __expf(T[k*4+0] - pmax[k]);
        T[k*4+1] = __expf(T[k*4+1] - pmax[k]);
        T[k*4+2] = __expf(T[k*4+2] - pmax[k]);
        T[k*4+3] = __expf(T[k*4+3] - pmax[k]);
        float s = (T[k*4+0] + T[k*4+1]) + (T[k*4+2] + T[k*4+3]);
        #pragma unroll
        for (int off = 32; off > 0; off >>= 1) s += __shfl_xor(s, off);
        if (lane == 0) redB[k][wv] = s;
    }
    __syncthreads();
    #pragma unroll
    for (int k = 0; k < H_; ++k) {
        float inv = 1.0f / ((redB[k][0] + redB[k][1]) + (redB[k][2] + redB[k][3]));
        T[k*4+0] *= inv; T[k*4+1] *= inv; T[k*4+2] *= inv; T[k*4+3] *= inv;
    }
    #pragma unroll
    for (int jj = 0; jj < H_; ++jj) {
        float u0 = bw_s[jj], u1 = u0, u2 = u0, u3 = u0;
        #pragma unroll
        for (int k = 0; k < H_; ++k) {
            float w = Ww_s[k * H_ + jj];
            u0 += T[k*4+0] * w; u1 += T[k*4+1] * w;
            u2 += T[k*4+2] * w; u3 += T[k*4+3] * w;
        }
        *(float4*)&attnP[rowbase + (size_t)jj * N_ * N_ + tid * 4] =
            make_float4(u0, u1, u2, u3);
    }
}

// ---------------- PV (batched): A = fp32 attn (converted on the fly), B = Vt bf16 ----------------
__global__ __launch_bounds__(128) void pv_gemm(const float* __restrict__ Pf,
    const u16* __restrict__ Vt, u16* __restrict__ Oh) {
  __shared__ u16 As[128][64], Bs[64][64];
  f32x4 acc[4][4] = {};
  const int z = blockIdx.y, b = z / H_, h = z % H_;
  const int row0 = blockIdx.x * 128;
  const float* Ap = Pf + (size_t)z * N_ * N_ + (size_t)row0 * N_;
  const u16* Bb = Vt + (size_t)z * D_ * N_;
  const int tid = threadIdx.x;
  for (int k0 = 0; k0 < N_; k0 += 64) {
    #pragma unroll
    for (int i = 0; i < 16; ++i) {
      const int row = i * 8 + (tid >> 4);
      const int c4 = (tid & 15) * 4;
      float4 v = *(const float4*)&Ap[(size_t)row * N_ + k0 + c4];
      *(ushort4*)&As[row][c4] = make_ushort4(f2bf(v.x), f2bf(v.y), f2bf(v.z), f2bf(v.w));
    }
    stage_bt<64, 2>(Bb + k0, N_, Bs);
    __syncthreads();
    mma_step<2, 1>(As, Bs, acc);
    __syncthreads();
  }
  const int lane = tid & 63, wv = tid >> 6;
  #pragma unroll
  for (int mi = 0; mi < 4; ++mi)
  #pragma unroll
  for (int ni = 0; ni < 4; ++ni) {
    const int c = ni * 16 + (lane & 15);
    const int rb = row0 + wv * 64 + mi * 16 + (lane >> 4) * 4;
    #pragma unroll
    for (int rr = 0; rr < 4; ++rr)
      Oh[(size_t)(b * N_ + rb + rr) * C_ + h * D_ + c] = f2bf(acc[mi][ni][rr]);
  }
}

// ---------------- proj GEMM: [4096,768] x [768,768] + bias -> fp32 out ----------------
__global__ __launch_bounds__(128) void proj_gemm(const u16* __restrict__ Oh,
    const u16* __restrict__ Wt, const float* __restrict__ bias, float* __restrict__ out) {
  __shared__ u16 As[64][64], Bs[128][64];
  f32x4 acc[4][4] = {};
  const int row0 = blockIdx.y * 64, col0 = blockIdx.x * 128;
  const u16* Ab = Oh + (size_t)row0 * C_;
  const u16* Bb = Wt + (size_t)col0 * C_;
  for (int k0 = 0; k0 < C_; k0 += 64) {
    stage_bt<64, 2>(Ab + k0, C_, As);
    stage_bt<128, 2>(Bb + k0, C_, Bs);
    __syncthreads();
    mma_step<1, 2>(As, Bs, acc);
    __syncthreads();
  }
  const int lane = threadIdx.x & 63, wv = threadIdx.x >> 6;
  const int wc = wv & 1;
  #pragma unroll
  for (int mi = 0; mi < 4; ++mi)
  #pragma unroll
  for (int ni = 0; ni < 4; ++ni) {
    const int c = col0 + wc * 64 + ni * 16 + (lane & 15);
    const int rb = row0 + mi * 16 + (lane >> 4) * 4;
    const float bv = bias[c];
    #pragma unroll
    for (int rr = 0; rr < 4; ++rr)
      out[(size_t)(rb + rr) * C_ + c] = acc[mi][ni][rr] + bv;
  }
}

extern "C" void kernel_launch(void* const* d_in, const int* in_sizes, int n_in,
                              void* d_out, int out_size, void* d_ws, size_t ws_size,
                              hipStream_t stream) {
  const float* x     = (const float*)d_in[0];
  const float* Wqkv  = (const float*)d_in[1];
  const float* bqkv  = (const float*)d_in[2];
  const float* Wl    = (const float*)d_in[3];
  const float* bl    = (const float*)d_in[4];
  const float* Ww    = (const float*)d_in[5];
  const float* bw    = (const float*)d_in[6];
  const float* Wproj = (const float*)d_in[7];
  const float* bproj = (const float*)d_in[8];

  float* out   = (float*)d_out;
  float* attnP = out + (size_t)MT * C_;            // logits scratch == final attn output

  u16* xbf = (u16*)d_ws;                           // [4096][768]
  u16* Wqt = xbf + (size_t)MT * C_;                // [2304][768] = W_qkv^T
  u16* Wpt = Wqt + (size_t)3 * C_ * C_;            // [768][768]  = W_proj^T
  u16* Qb  = Wpt + (size_t)C_ * C_;                // [4096][768] (scaled)
  u16* Kb  = Qb + (size_t)MT * C_;                 // [4096][768]
  u16* Vb  = Kb + (size_t)MT * C_;                 // [4096][768] row-major
  u16* Vtb = Vb + (size_t)MT * C_;                 // [b][h][d][n]
  u16* Oh  = Vtb + (size_t)MT * C_;                // [4096][768]
  // total ws use: ~42.5 MB

  cvt_bf16<<<(MT * C_ / 4 + 255) / 256, 256, 0, stream>>>(x, xbf, MT * C_ / 4);
  transpose_bf16<<<dim3(3 * C_ / 32, C_ / 32), dim3(32, 8), 0, stream>>>(Wqkv, Wqt, C_, 3 * C_);
  transpose_bf16<<<dim3(C_ / 32, C_ / 32), dim3(32, 8), 0, stream>>>(Wproj, Wpt, C_, C_);

  qkv_gemm<<<dim3(3 * C_ / 128, MT / 128), 256, 0, stream>>>(xbf, Wqt, bqkv, Qb, Kb, Vb);
  transpose_v<<<dim3(C_ / 32, N_ / 32, B_), dim3(32, 8), 0, stream>>>(Vb, Vtb);
  qk_gemm<<<dim3(N_ / 128, N_ / 128, B_ * H_), 256, 0, stream>>>(Qb, Kb, attnP);
  talking_softmax<<<MT, 256, 0, stream>>>(attnP, Wl, bl, Ww, bw);
  pv_gemm<<<dim3(N_ / 128, B_ * H_), 128, 0, stream>>>(attnP, Vtb, Oh);
  proj_gemm<<<dim3(C_ / 128, MT / 64), 128, 0, stream>>>(Oh, Wpt, bproj, out);
}